// Round 2
// baseline (833.434 us; speedup 1.0000x reference)
//
#include <hip/hip_runtime.h>
#include <stdint.h>

// ============================================================================
// MoE adapter layer, sparse top-2 dispatch, bf16 MFMA expert GEMMs.
// R5: k_gemm moved from 2-phase (vmcnt(0)-drain per K-step; MfmaUtil 14.5%)
//     to the 8-phase counted-vmcnt schedule (T3+T4+T5, m218/m248):
//     per K-tile 4 phases {stage 1 half-tile of t+1; ds_read quadrant;
//     setprio(1) 16xMFMA setprio(0)}, raw s_barrier only at P0 (after
//     s_waitcnt vmcnt(2)) and end of P3. Loads for tile t+1 stay in flight
//     across barriers; vmcnt never drains to 0 in the loop.
//     Hazards: RAW buf[c] <- vmcnt(2)+barrier (tile t's 8 loads are oldest);
//     WAR both bufs <- P3-end barrier (ds_reads lgkm-complete before MFMA).
//     GEMM2 split-K 2->4 for round balance (320 -> 640 blocks).
// Gating kept entirely fp32 (top-k decision boundaries are flip-sensitive).
// ============================================================================

typedef __attribute__((ext_vector_type(4))) float floatx4;
typedef __attribute__((ext_vector_type(8))) short shortx8;
typedef unsigned short ushort_t;

#define T_TOKENS 4096
#define D_DIM    1024
#define E_EXP    8
#define H_DIM    4096
#define P_DIM    256
#define ROWS_PAD 10240  // 8192 rows + per-expert 256-padding (max 10232)
#define MBLK     40     // ROWS_PAD / 256

__device__ __forceinline__ ushort_t f2bf(float f) {
  union { float f; unsigned int u; } c; c.f = f;
  unsigned int u = c.u;
  unsigned int r = u + 0x7FFFu + ((u >> 16) & 1u);  // RNE
  return (ushort_t)(r >> 16);
}

__device__ __forceinline__ void stage16(const ushort_t* g, ushort_t* l) {
  __builtin_amdgcn_global_load_lds((const __attribute__((address_space(1))) void*)g,
                                   (__attribute__((address_space(3))) void*)l, 16, 0, 0);
}

// ---------------------------------------------------------------- convert
__global__ __launch_bounds__(256) void k_cvt(const float* __restrict__ src,
                                             ushort_t* __restrict__ dst, int n4) {
  int g = blockIdx.x * 256 + threadIdx.x;
  if (g >= n4) return;
  floatx4 v = ((const floatx4*)src)[g];
  ushort4 o; o.x = f2bf(v.x); o.y = f2bf(v.y); o.z = f2bf(v.z); o.w = f2bf(v.w);
  ((ushort4*)dst)[g] = o;
}

// ---------------------------------------------------------------- small init
__global__ __launch_bounds__(256) void k_small_init(int* counts, int* cursor,
                                                    float* frac_sum, int* row2tok) {
  int g = blockIdx.x * 256 + threadIdx.x;
  if (g < 8) { counts[g] = 0; cursor[g] = 0; frac_sum[g] = 0.f; }
  if (g < ROWS_PAD) row2tok[g] = -1;
}

// ---------------------------------------------------------------- proj = x @ Wp^T + bp   (fp32)
__global__ __launch_bounds__(256) void k_proj(const float* __restrict__ x,
                                              const float* __restrict__ Wp,
                                              const float* __restrict__ bp,
                                              float* __restrict__ proj) {
  __shared__ float Wc[256 * 36];
  __shared__ float Xc[16 * 36];
  int tid = threadIdx.x;
  int t0 = blockIdx.x * 16;
  int cg = tid & 31, tg = tid >> 5;
  floatx4 acc[2][8];
#pragma unroll
  for (int a = 0; a < 2; a++)
#pragma unroll
    for (int b = 0; b < 8; b++) acc[a][b] = (floatx4){0.f, 0.f, 0.f, 0.f};
  for (int kc = 0; kc < 32; ++kc) {
    int k0 = kc * 32;
    __syncthreads();
#pragma unroll
    for (int it = 0; it < 8; ++it) {
      int f = it * 256 + tid;
      int j = f >> 3, kk = (f & 7) << 2;
      floatx4 v = *(const floatx4*)(Wp + j * 1024 + k0 + kk);
      *(floatx4*)(Wc + j * 36 + kk) = v;
    }
    if (tid < 128) {
      int t = tid >> 3, kk = (tid & 7) << 2;
      floatx4 v = *(const floatx4*)(x + (size_t)(t0 + t) * 1024 + k0 + kk);
      *(floatx4*)(Xc + t * 36 + kk) = v;
    }
    __syncthreads();
#pragma unroll
    for (int k4 = 0; k4 < 8; ++k4) {
      floatx4 xv[2], wv[8];
#pragma unroll
      for (int tt = 0; tt < 2; tt++) xv[tt] = *(floatx4*)(Xc + (tg * 2 + tt) * 36 + k4 * 4);
#pragma unroll
      for (int jj = 0; jj < 8; jj++) wv[jj] = *(floatx4*)(Wc + (cg + jj * 32) * 36 + k4 * 4);
#pragma unroll
      for (int tt = 0; tt < 2; tt++)
#pragma unroll
        for (int jj = 0; jj < 8; jj++) acc[tt][jj] += xv[tt] * wv[jj];
    }
  }
#pragma unroll
  for (int tt = 0; tt < 2; tt++)
#pragma unroll
    for (int jj = 0; jj < 8; jj++) {
      floatx4 a = acc[tt][jj];
      float s = (a.x + a.y) + (a.z + a.w);
      int t = t0 + tg * 2 + tt, j = cg + jj * 32;
      proj[t * 256 + j] = s + bp[j];
    }
}

// ---------------------------------------------------------------- gate
__global__ __launch_bounds__(128) void k_gate(const float* __restrict__ proj,
                                              const float* __restrict__ sim,
                                              const float* __restrict__ temp,
                                              int* __restrict__ topi, float* __restrict__ wslot,
                                              float* __restrict__ swsum,
                                              float* __restrict__ frac_sum, int* __restrict__ counts) {
  __shared__ float simT[8][256];
  __shared__ float snorm[8];
  __shared__ float fracs[8];
  __shared__ int cnts[8];
  int tid = threadIdx.x;
  for (int i = tid; i < 2048; i += 128) { int p = i >> 3, e = i & 7; simT[e][p] = sim[i]; }
  if (tid < 8) { fracs[tid] = 0.f; cnts[tid] = 0; }
  __syncthreads();
  if (tid < 8) {
    float s = 0.f;
    for (int p = 0; p < 256; p++) { float v = simT[tid][p]; s += v * v; }
    snorm[tid] = fmaxf(sqrtf(s), 1e-12f);
  }
  __syncthreads();
  int t = blockIdx.x * 128 + tid;
  floatx4 n4 = (floatx4){0.f, 0.f, 0.f, 0.f};
  floatx4 d4[8];
#pragma unroll
  for (int e = 0; e < 8; e++) d4[e] = (floatx4){0.f, 0.f, 0.f, 0.f};
  const floatx4* pr = (const floatx4*)(proj + t * 256);
  for (int k4 = 0; k4 < 64; ++k4) {
    floatx4 p = pr[k4];
    n4 += p * p;
#pragma unroll
    for (int e = 0; e < 8; e++) d4[e] += p * *(const floatx4*)(&simT[e][k4 * 4]);
  }
  float nrm = fmaxf(sqrtf((n4.x + n4.y) + (n4.z + n4.w)), 1e-12f);
  float scale = expf(fminf(temp[0], 4.6051701859880914f));  // log(100)
  float pe[8];
  float mx = -1e30f;
#pragma unroll
  for (int e = 0; e < 8; e++) {
    float d = (d4[e].x + d4[e].y) + (d4[e].z + d4[e].w);
    pe[e] = d / (nrm * snorm[e]) * scale;
    mx = fmaxf(mx, pe[e]);
  }
  float sum = 0.f;
#pragma unroll
  for (int e = 0; e < 8; e++) { pe[e] = expf(pe[e] - mx); sum += pe[e]; }
#pragma unroll
  for (int e = 0; e < 8; e++) pe[e] /= sum;
  int i0 = 0;
#pragma unroll
  for (int e = 1; e < 8; e++) if (pe[e] > pe[i0]) i0 = e;
  int i1 = (i0 == 0) ? 1 : 0;
#pragma unroll
  for (int e = 0; e < 8; e++) if (e != i1 && e != i0 && pe[e] > pe[i1]) i1 = e;
  float v0 = pe[i0], v1 = pe[i1];
  float s2 = v0 + v1 + 1e-8f;
  float w0 = v0 / s2, w1 = v1 / s2;
  topi[t * 2] = i0; topi[t * 2 + 1] = i1;
  wslot[t * 2] = w0; wslot[t * 2 + 1] = w1;
  swsum[t] = w0 + w1;
#pragma unroll
  for (int e = 0; e < 8; e++) atomicAdd(&fracs[e], pe[e]);
  atomicAdd(&cnts[i0], 1); atomicAdd(&cnts[i1], 1);
  __syncthreads();
  if (tid < 8) { atomicAdd(&frac_sum[tid], fracs[tid]); atomicAdd(&counts[tid], cnts[tid]); }
}

// ---------------------------------------------------------------- scan (256-aligned expert segments)
__global__ void k_scan(const int* __restrict__ counts, const float* __restrict__ frac_sum,
                       int* __restrict__ offsets, int* __restrict__ blk2e,
                       float* __restrict__ out_tail) {
  __shared__ int offs[9];
  if (threadIdx.x == 0) {
    int off = 0;
    for (int e = 0; e < 8; e++) { offs[e] = off; off += ((counts[e] + 255) >> 8) << 8; }
    offs[8] = off;
    for (int e = 0; e < 9; e++) offsets[e] = offs[e];
    float aux = 0.f;
    for (int e = 0; e < 8; e++) { float fr = frac_sum[e] / 4096.f; aux += (fr - 0.125f) * (fr - 0.125f); }
    out_tail[0] = aux;
  }
  __syncthreads();
  int tid = threadIdx.x;
  if (tid < MBLK) {
    int r = tid * 256, e = -1;
    for (int q = 0; q < 8; q++) if (r >= offs[q] && r < offs[q + 1]) e = q;
    blk2e[tid] = e;
  }
  if (tid < 8) {
    out_tail[1 + tid] = frac_sum[tid] / 4096.f;
    out_tail[9 + tid] = (float)counts[tid];
  }
}

// ---------------------------------------------------------------- assign rows
__global__ __launch_bounds__(256) void k_assign(const int* __restrict__ topi,
                                                const float* __restrict__ wslot,
                                                const int* __restrict__ offsets,
                                                int* __restrict__ cursor,
                                                int* __restrict__ row2tok, float* __restrict__ roww) {
  int g = blockIdx.x * 256 + threadIdx.x;
  if (g >= 8192) return;
  int t = g >> 1;
  int e = topi[g];
  int pos = atomicAdd(&cursor[e], 1);
  int r = offsets[e] + pos;
  row2tok[r] = t;
  roww[r] = wslot[g];
}

// ---------------------------------------------------------------- gather x rows -> bf16
__global__ __launch_bounds__(64) void k_gather(const float* __restrict__ x,
                                               const int* __restrict__ row2tok,
                                               ushort_t* __restrict__ xg) {
  int r = blockIdx.x;
  int t = row2tok[r];
  ushort4* dst = (ushort4*)(xg + (size_t)r * 1024);
  if (t < 0) {
    ushort4 z; z.x = z.y = z.z = z.w = 0;
    for (int i = threadIdx.x; i < 256; i += 64) dst[i] = z;
  } else {
    const floatx4* src = (const floatx4*)(x + (size_t)t * 1024);
    for (int i = threadIdx.x; i < 256; i += 64) {
      floatx4 v = src[i];
      ushort4 o; o.x = f2bf(v.x); o.y = f2bf(v.y); o.z = f2bf(v.z); o.w = f2bf(v.w);
      dst[i] = o;
    }
  }
}

// ---------------------------------------------------------------- out = (w0+w1) * x
__global__ __launch_bounds__(256) void k_init_out(const float* __restrict__ x,
                                                  const float* __restrict__ swsum,
                                                  float* __restrict__ out) {
  int g = blockIdx.x * 256 + threadIdx.x;
  float s = swsum[g >> 8];
  floatx4 v = ((const floatx4*)x)[g];
  ((floatx4*)out)[g] = v * s;
}

// ---------------------------------------------------------------- bf16 MFMA GEMM (NT)
// 256x256 tile, BK=64, 512 threads = 8 waves (2M x 4N), per-wave 128x64 out.
// LDS: [2 dbuf][2 half][128x64] for A and B (128 KB). Half-tiles staged via
// global_load_lds(16B) with source-side XOR chunk swizzle (read uses same
// XOR -> involution; 0 bank conflicts measured).
// Per K-tile t (buf c=t&1), 4 phases; stages target buf c^1 (tile t+1):
//   P0: stage A-half0(t+1); s_waitcnt vmcnt(2); s_barrier; ds_read q0(8);
//       setprio(1) 16xMFMA setprio(0)
//   P1: stage A-half1(t+1); ds_read q1(4); 16xMFMA
//   P2: stage B-half0(t+1); ds_read q2(8); 16xMFMA
//   P3: stage B-half1(t+1); ds_read q3(4); 16xMFMA; s_barrier
// vmcnt never drains to 0 in the loop; loads span barriers (T4).
// mode 1 (hout!=0): h = Aop @ W^T + bias -> bf16
// mode 2 (hout==0): f = Aop @ W^T (+bias iff z==0); atomicAdd(out[tok], roww*f)
__global__ __launch_bounds__(512, 2) void k_gemm(const ushort_t* __restrict__ Aop0,
                                                 const ushort_t* __restrict__ Wall,
                                                 const float* __restrict__ bias,
                                                 const int* __restrict__ blk2e,
                                                 int K, int N,
                                                 ushort_t* __restrict__ hout,
                                                 float* __restrict__ outp,
                                                 const int* __restrict__ row2tok,
                                                 const float* __restrict__ roww) {
  // m204 bijective XCD-chunked swizzle over (x,y) grid
  int gx = gridDim.x;
  int nwg = gx * gridDim.y;
  int flat = blockIdx.y * gx + blockIdx.x;
  int qq = nwg >> 3, rr = nwg & 7;
  int xcd = flat & 7, idx = flat >> 3;
  int swz = (xcd < rr ? xcd * (qq + 1) : rr * (qq + 1) + (xcd - rr) * qq) + idx;
  int rb = swz / gx, nb = swz - rb * gx;

  int e = blk2e[rb];
  if (e < 0) return;
  int Kslice = K / gridDim.z;
  int kbase = blockIdx.z * Kslice;
  const ushort_t* Aop = Aop0 + (size_t)rb * 256 * K + kbase;
  const ushort_t* Bop = Wall + (size_t)e * N * K + (size_t)nb * 256 * K + kbase;

  __shared__ ushort_t As[2][2][8192];   // [dbuf][half][128*64]
  __shared__ ushort_t Bs[2][2][8192];

  int tid = threadIdx.x, lane = tid & 63, wv = tid >> 6;
  int l15 = lane & 15, q = lane >> 4;
  int wm = (wv >> 2) << 7;   // 0 or 128 -> A-half = wv>>2
  int wn = (wv & 3) << 6;    // 0..192  -> B-half = (wv>>1)&1
  int ha = wv >> 2;
  int hb = (wv >> 1) & 1;
  int bn = wn & 127;         // n-base within B-half (0 or 64)

  floatx4 acc[8][4];
#pragma unroll
  for (int i = 0; i < 8; i++)
#pragma unroll
    for (int j = 0; j < 4; j++) acc[i][j] = (floatx4){0.f, 0.f, 0.f, 0.f};

  // staging geometry: per half-tile (128 rows x 64 cols), 2 issues/thread.
  //   issue r: row = r*64 + (tid>>3), chunk slot = tid&7;
  //   global col-chunk pre-swizzled: slot ^ (row&7); LDS dest linear.
  int srow = tid >> 3;
  int schunk = tid & 7;
  int ksteps = Kslice >> 6;
  int cur = 0;

  auto stage_half = [&](const ushort_t* gbase, int half, int kt, ushort_t* lds) {
#pragma unroll
    for (int r = 0; r < 2; ++r) {
      int rowh = (r << 6) + srow;
      size_t goff = (size_t)((half << 7) + rowh) * (size_t)K + (size_t)(kt << 6) +
                    (size_t)((schunk ^ (rowh & 7)) << 3);
      stage16(gbase + goff, lds + ((r << 9) + (wv << 6)) * 8);
    }
  };

  // prologue: stage all 4 half-tiles of K-tile 0 into buf 0 (8 loads/thread)
  stage_half(Aop, 0, 0, &As[0][0][0]);
  stage_half(Aop, 1, 0, &As[0][1][0]);
  stage_half(Bop, 0, 0, &Bs[0][0][0]);
  stage_half(Bop, 1, 0, &Bs[0][1][0]);

  for (int kt = 0; kt < ksteps; ++kt) {
    int ktn = (kt + 1 < ksteps) ? kt + 1 : kt;   // clamped re-stage on last tile
    const ushort_t* Ab = &As[cur][ha][0];
    const ushort_t* Bb = &Bs[cur][hb][0];
    ushort_t* AsN = &As[cur ^ 1][0][0];
    ushort_t* BsN = &Bs[cur ^ 1][0][0];

    shortx8 af[4], bfv[4];

    // ---- P0: stage A-half0(t+1); validate buf cur; quadrant (kc=0, i=0..3)
    stage_half(Aop, 0, ktn, AsN);
    asm volatile("s_waitcnt vmcnt(2)" ::: "memory");
    __builtin_amdgcn_s_barrier();
    __builtin_amdgcn_sched_barrier(0);
#pragma unroll
    for (int i = 0; i < 4; ++i) {
      int row = i * 16 + l15;
      af[i] = *(const shortx8*)(Ab + (row << 6) + ((q ^ (row & 7)) << 3));
    }
#pragma unroll
    for (int j = 0; j < 4; ++j) {
      int row = bn + j * 16 + l15;
      bfv[j] = *(const shortx8*)(Bb + (row << 6) + ((q ^ (row & 7)) << 3));
    }
    __builtin_amdgcn_s_setprio(1);
#pragma unroll
    for (int i = 0; i < 4; ++i)
#pragma unroll
      for (int j = 0; j < 4; ++j)
        acc[i][j] = __builtin_amdgcn_mfma_f32_16x16x32_bf16(af[i], bfv[j], acc[i][j], 0, 0, 0);
    __builtin_amdgcn_s_setprio(0);

    // ---- P1: stage A-half1(t+1); quadrant (kc=0, i=4..7)
    stage_half(Aop, 1, ktn, AsN + 8192);
#pragma unroll
    for (int i = 0; i < 4; ++i) {
      int row = (i + 4) * 16 + l15;
      af[i] = *(const shortx8*)(Ab + (row << 6) + ((q ^ (row & 7)) << 3));
    }
    __builtin_amdgcn_s_setprio(1);
#pragma unroll
    for (int i = 0; i < 4; ++i)
#pragma unroll
      for (int j = 0; j < 4; ++j)
        acc[i + 4][j] = __builtin_amdgcn_mfma_f32_16x16x32_bf16(af[i], bfv[j], acc[i + 4][j], 0, 0, 0);
    __builtin_amdgcn_s_setprio(0);

    // ---- P2: stage B-half0(t+1); quadrant (kc=1, i=0..3)
    stage_half(Bop, 0, ktn, BsN);
#pragma unroll
    for (int i = 0; i < 4; ++i) {
      int row = i * 16 + l15;
      af[i] = *(const shortx8*)(Ab + (row << 6) + (((4 + q) ^ (row & 7)) << 3));
    }
#pragma unroll
    for (int j = 0; j < 4; ++j) {
      int row = bn + j * 16 + l15;
      bfv[j] = *(const shortx8*)(Bb + (row << 6) + (((4 + q) ^ (row & 7)) << 3));
    }
    __builtin_amdgcn_s_setprio(1);
#pragma unroll
    for (int i = 0; i < 4; ++i)
#pragma unroll
      for (int j = 0; j < 4; ++j)
        acc[i][j] = __builtin_amdgcn_mfma_f32_16x16x32_bf16(af[i], bfv[j], acc[i][j], 0, 0, 0);
    __builtin_amdgcn_s_setprio(0);

    // ---- P3: stage B-half1(t+1); quadrant (kc=1, i=4..7); end-of-tile barrier
    stage_half(Bop, 1, ktn, BsN + 8192);
#pragma unroll
    for (int i = 0; i < 4; ++i) {
      int row = (i + 4) * 16 + l15;
      af[i] = *(const shortx8*)(Ab + (row << 6) + (((4 + q) ^ (row & 7)) << 3));
    }
    __builtin_amdgcn_s_setprio(1);
#pragma unroll
    for (int i = 0; i < 4; ++i)
#pragma unroll
      for (int j = 0; j < 4; ++j)
        acc[i + 4][j] = __builtin_amdgcn_mfma_f32_16x16x32_bf16(af[i], bfv[j], acc[i + 4][j], 0, 0, 0);
    __builtin_amdgcn_s_setprio(0);
    __builtin_amdgcn_s_barrier();          // reads of buf cur done before next
    __builtin_amdgcn_sched_barrier(0);     // tile's stages overwrite it
    cur ^= 1;
  }

  const float* be = bias + (size_t)e * N + (size_t)nb * 256;
  if (hout) {
    ushort_t* hp = hout + (size_t)(rb * 256) * N + nb * 256;
#pragma unroll
    for (int j = 0; j < 4; ++j) {
      int n = wn + j * 16 + l15;
      float bv = be[n];
#pragma unroll
      for (int i = 0; i < 8; ++i)
#pragma unroll
        for (int r = 0; r < 4; ++r) {
          int m = wm + i * 16 + (q << 2) + r;          // D row = quad*4 + reg
          hp[(size_t)m * N + n] = f2bf(acc[i][j][r] + bv);
        }
    }
  } else {
    bool addb = (blockIdx.z == 0);
    float bvv[4];
#pragma unroll
    for (int j = 0; j < 4; ++j) bvv[j] = addb ? be[wn + j * 16 + l15] : 0.f;
#pragma unroll
    for (int i = 0; i < 8; ++i)
#pragma unroll
      for (int r = 0; r < 4; ++r) {
        int m = wm + i * 16 + (q << 2) + r;
        int grow = rb * 256 + m;
        int tok = row2tok[grow];
        if (tok < 0) continue;
        float w = roww[grow];
        float* op = outp + (size_t)tok * 1024 + nb * 256;
#pragma unroll
        for (int j = 0; j < 4; ++j) {
          int n = wn + j * 16 + l15;
          atomicAdd(op + n, (acc[i][j][r] + bvv[j]) * w);
        }
      }
  }
}

// ============================================================================
extern "C" void kernel_launch(void* const* d_in, const int* in_sizes, int n_in,
                              void* d_out, int out_size, void* d_ws, size_t ws_size,
                              hipStream_t stream) {
  (void)in_sizes; (void)n_in; (void)out_size; (void)ws_size;
  const float* x      = (const float*)d_in[0];
  const float* Wp     = (const float*)d_in[1];
  const float* bp     = (const float*)d_in[2];
  const float* sim    = (const float*)d_in[3];
  const float* temp   = (const float*)d_in[4];
  const float* A      = (const float*)d_in[5];
  const float* a_bias = (const float*)d_in[6];
  const float* Bw     = (const float*)d_in[7];
  const float* b_bias = (const float*)d_in[8];
  float* out = (float*)d_out;

  char* ws = (char*)d_ws;
  ushort_t* Abf    = (ushort_t*)(ws);                     //  67,108,864 B
  ushort_t* Bbf    = (ushort_t*)(ws + 67108864);          //  67,108,864 B
  ushort_t* xg     = (ushort_t*)(ws + 134217728);         //  20,971,520 B
  ushort_t* h      = (ushort_t*)(ws + 155189248);         //  83,886,080 B
  float*    proj   = (float*)   (ws + 239075328);         //   4,194,304 B
  int*      topi   = (int*)     (ws + 243269632);
  float*    wslot  = (float*)   (ws + 243302400);
  float*    swsum  = (float*)   (ws + 243335168);
  int*      row2tok= (int*)     (ws + 243351552);
  float*    roww   = (float*)   (ws + 243392512);
  int*      counts = (int*)     (ws + 243433472);
  int*      cursor = (int*)     (ws + 243433504);
  int*      offsets= (int*)     (ws + 243433536);
  int*      blk2e  = (int*)     (ws + 243433600);
  float*    fracs  = (float*)   (ws + 243433760);

  k_cvt<<<32768, 256, 0, stream>>>(A,  Abf, 8388608);
  k_cvt<<<32768, 256, 0, stream>>>(Bw, Bbf, 8388608);
  k_small_init<<<40, 256, 0, stream>>>(counts, cursor, fracs, row2tok);
  k_proj<<<256, 256, 0, stream>>>(x, Wp, bp, proj);
  k_gate<<<32, 128, 0, stream>>>(proj, sim, temp, topi, wslot, swsum, fracs, counts);
  k_scan<<<1, 128, 0, stream>>>(counts, fracs, offsets, blk2e, out + 4194304);
  k_assign<<<32, 256, 0, stream>>>(topi, wslot, offsets, cursor, row2tok, roww);
  k_gather<<<ROWS_PAD, 64, 0, stream>>>(x, row2tok, xg);
  k_init_out<<<4096, 256, 0, stream>>>(x, swsum, out);
  // GEMM1: h[r][j] = xg[r] . A_e[j] + a_bias  (K=1024, N=4096), grid 16x40
  k_gemm<<<dim3(16, MBLK, 1), 512, 0, stream>>>(xg, Abf, a_bias, blk2e, 1024, 4096,
                                                h, nullptr, nullptr, nullptr);
  // GEMM2: f = h . B_e^T + b_bias; out[tok] += roww * f  (K=4096, N=1024, split-K x4)
  k_gemm<<<dim3(4, MBLK, 4), 512, 0, stream>>>(h, Bbf, b_bias, blk2e, 4096, 1024,
                                               nullptr, out, row2tok, roww);
}

// Round 3
// 773.865 us; speedup vs baseline: 1.0770x; 1.0770x over previous
//
#include <hip/hip_runtime.h>
#include <stdint.h>

// ============================================================================
// MoE adapter layer, sparse top-2 dispatch, bf16 MFMA expert GEMMs.
// R6: differential round.
//  - GEMMs split into named kernels (k_gemm1 / k_gemm2) for counter attribution.
//  - k_gemm1: m97-style 128x128 tile, BK=64, 256 thr / 4 waves, acc 4x4,
//    dbuf 64 KB LDS, gload_lds(16B) + source-XOR swizzle, simple 2-phase loop.
//    2 blocks/CU -> cross-block latency hiding (m97/m103: 874-912 TF; m102:
//    833 TF at N=4096 with this structure).
//  - k_gemm2: reverted to R4's 256x256 2-phase, split-K=2 (best measured);
//    serves as the in-run A/B comparator (one structural variable changed).
//  - R5's 4-phase counted-vmcnt schedule removed (regressed 204->228,
//    matching m196/m232: coarse phase-split off-template hurts).
// Gating kept entirely fp32 (top-k decision boundaries are flip-sensitive).
// ============================================================================

typedef __attribute__((ext_vector_type(4))) float floatx4;
typedef __attribute__((ext_vector_type(8))) short shortx8;
typedef unsigned short ushort_t;

#define T_TOKENS 4096
#define D_DIM    1024
#define E_EXP    8
#define H_DIM    4096
#define P_DIM    256
#define ROWS_PAD 10240  // 8192 rows + per-expert 256-padding (max 10232)
#define MBLK     40     // ROWS_PAD / 256   (k_gemm2 row-blocks)
#define MBLK1    80     // ROWS_PAD / 128   (k_gemm1 row-blocks)

__device__ __forceinline__ ushort_t f2bf(float f) {
  union { float f; unsigned int u; } c; c.f = f;
  unsigned int u = c.u;
  unsigned int r = u + 0x7FFFu + ((u >> 16) & 1u);  // RNE
  return (ushort_t)(r >> 16);
}

__device__ __forceinline__ void stage16(const ushort_t* g, ushort_t* l) {
  __builtin_amdgcn_global_load_lds((const __attribute__((address_space(1))) void*)g,
                                   (__attribute__((address_space(3))) void*)l, 16, 0, 0);
}

// ---------------------------------------------------------------- convert
__global__ __launch_bounds__(256) void k_cvt(const float* __restrict__ src,
                                             ushort_t* __restrict__ dst, int n4) {
  int g = blockIdx.x * 256 + threadIdx.x;
  if (g >= n4) return;
  floatx4 v = ((const floatx4*)src)[g];
  ushort4 o; o.x = f2bf(v.x); o.y = f2bf(v.y); o.z = f2bf(v.z); o.w = f2bf(v.w);
  ((ushort4*)dst)[g] = o;
}

// ---------------------------------------------------------------- small init
__global__ __launch_bounds__(256) void k_small_init(int* counts, int* cursor,
                                                    float* frac_sum, int* row2tok) {
  int g = blockIdx.x * 256 + threadIdx.x;
  if (g < 8) { counts[g] = 0; cursor[g] = 0; frac_sum[g] = 0.f; }
  if (g < ROWS_PAD) row2tok[g] = -1;
}

// ---------------------------------------------------------------- proj = x @ Wp^T + bp   (fp32)
__global__ __launch_bounds__(256) void k_proj(const float* __restrict__ x,
                                              const float* __restrict__ Wp,
                                              const float* __restrict__ bp,
                                              float* __restrict__ proj) {
  __shared__ float Wc[256 * 36];
  __shared__ float Xc[16 * 36];
  int tid = threadIdx.x;
  int t0 = blockIdx.x * 16;
  int cg = tid & 31, tg = tid >> 5;
  floatx4 acc[2][8];
#pragma unroll
  for (int a = 0; a < 2; a++)
#pragma unroll
    for (int b = 0; b < 8; b++) acc[a][b] = (floatx4){0.f, 0.f, 0.f, 0.f};
  for (int kc = 0; kc < 32; ++kc) {
    int k0 = kc * 32;
    __syncthreads();
#pragma unroll
    for (int it = 0; it < 8; ++it) {
      int f = it * 256 + tid;
      int j = f >> 3, kk = (f & 7) << 2;
      floatx4 v = *(const floatx4*)(Wp + j * 1024 + k0 + kk);
      *(floatx4*)(Wc + j * 36 + kk) = v;
    }
    if (tid < 128) {
      int t = tid >> 3, kk = (tid & 7) << 2;
      floatx4 v = *(const floatx4*)(x + (size_t)(t0 + t) * 1024 + k0 + kk);
      *(floatx4*)(Xc + t * 36 + kk) = v;
    }
    __syncthreads();
#pragma unroll
    for (int k4 = 0; k4 < 8; ++k4) {
      floatx4 xv[2], wv[8];
#pragma unroll
      for (int tt = 0; tt < 2; tt++) xv[tt] = *(floatx4*)(Xc + (tg * 2 + tt) * 36 + k4 * 4);
#pragma unroll
      for (int jj = 0; jj < 8; jj++) wv[jj] = *(floatx4*)(Wc + (cg + jj * 32) * 36 + k4 * 4);
#pragma unroll
      for (int tt = 0; tt < 2; tt++)
#pragma unroll
        for (int jj = 0; jj < 8; jj++) acc[tt][jj] += xv[tt] * wv[jj];
    }
  }
#pragma unroll
  for (int tt = 0; tt < 2; tt++)
#pragma unroll
    for (int jj = 0; jj < 8; jj++) {
      floatx4 a = acc[tt][jj];
      float s = (a.x + a.y) + (a.z + a.w);
      int t = t0 + tg * 2 + tt, j = cg + jj * 32;
      proj[t * 256 + j] = s + bp[j];
    }
}

// ---------------------------------------------------------------- gate
__global__ __launch_bounds__(128) void k_gate(const float* __restrict__ proj,
                                              const float* __restrict__ sim,
                                              const float* __restrict__ temp,
                                              int* __restrict__ topi, float* __restrict__ wslot,
                                              float* __restrict__ swsum,
                                              float* __restrict__ frac_sum, int* __restrict__ counts) {
  __shared__ float simT[8][256];
  __shared__ float snorm[8];
  __shared__ float fracs[8];
  __shared__ int cnts[8];
  int tid = threadIdx.x;
  for (int i = tid; i < 2048; i += 128) { int p = i >> 3, e = i & 7; simT[e][p] = sim[i]; }
  if (tid < 8) { fracs[tid] = 0.f; cnts[tid] = 0; }
  __syncthreads();
  if (tid < 8) {
    float s = 0.f;
    for (int p = 0; p < 256; p++) { float v = simT[tid][p]; s += v * v; }
    snorm[tid] = fmaxf(sqrtf(s), 1e-12f);
  }
  __syncthreads();
  int t = blockIdx.x * 128 + tid;
  floatx4 n4 = (floatx4){0.f, 0.f, 0.f, 0.f};
  floatx4 d4[8];
#pragma unroll
  for (int e = 0; e < 8; e++) d4[e] = (floatx4){0.f, 0.f, 0.f, 0.f};
  const floatx4* pr = (const floatx4*)(proj + t * 256);
  for (int k4 = 0; k4 < 64; ++k4) {
    floatx4 p = pr[k4];
    n4 += p * p;
#pragma unroll
    for (int e = 0; e < 8; e++) d4[e] += p * *(const floatx4*)(&simT[e][k4 * 4]);
  }
  float nrm = fmaxf(sqrtf((n4.x + n4.y) + (n4.z + n4.w)), 1e-12f);
  float scale = expf(fminf(temp[0], 4.6051701859880914f));  // log(100)
  float pe[8];
  float mx = -1e30f;
#pragma unroll
  for (int e = 0; e < 8; e++) {
    float d = (d4[e].x + d4[e].y) + (d4[e].z + d4[e].w);
    pe[e] = d / (nrm * snorm[e]) * scale;
    mx = fmaxf(mx, pe[e]);
  }
  float sum = 0.f;
#pragma unroll
  for (int e = 0; e < 8; e++) { pe[e] = expf(pe[e] - mx); sum += pe[e]; }
#pragma unroll
  for (int e = 0; e < 8; e++) pe[e] /= sum;
  int i0 = 0;
#pragma unroll
  for (int e = 1; e < 8; e++) if (pe[e] > pe[i0]) i0 = e;
  int i1 = (i0 == 0) ? 1 : 0;
#pragma unroll
  for (int e = 0; e < 8; e++) if (e != i1 && e != i0 && pe[e] > pe[i1]) i1 = e;
  float v0 = pe[i0], v1 = pe[i1];
  float s2 = v0 + v1 + 1e-8f;
  float w0 = v0 / s2, w1 = v1 / s2;
  topi[t * 2] = i0; topi[t * 2 + 1] = i1;
  wslot[t * 2] = w0; wslot[t * 2 + 1] = w1;
  swsum[t] = w0 + w1;
#pragma unroll
  for (int e = 0; e < 8; e++) atomicAdd(&fracs[e], pe[e]);
  atomicAdd(&cnts[i0], 1); atomicAdd(&cnts[i1], 1);
  __syncthreads();
  if (tid < 8) { atomicAdd(&frac_sum[tid], fracs[tid]); atomicAdd(&counts[tid], cnts[tid]); }
}

// ---------------------------------------------------------------- scan (256-aligned expert segments)
__global__ void k_scan(const int* __restrict__ counts, const float* __restrict__ frac_sum,
                       int* __restrict__ offsets, int* __restrict__ blk2e,
                       float* __restrict__ out_tail) {
  __shared__ int offs[9];
  if (threadIdx.x == 0) {
    int off = 0;
    for (int e = 0; e < 8; e++) { offs[e] = off; off += ((counts[e] + 255) >> 8) << 8; }
    offs[8] = off;
    for (int e = 0; e < 9; e++) offsets[e] = offs[e];
    float aux = 0.f;
    for (int e = 0; e < 8; e++) { float fr = frac_sum[e] / 4096.f; aux += (fr - 0.125f) * (fr - 0.125f); }
    out_tail[0] = aux;
  }
  __syncthreads();
  int tid = threadIdx.x;
  if (tid < MBLK) {
    int r = tid * 256, e = -1;
    for (int q = 0; q < 8; q++) if (r >= offs[q] && r < offs[q + 1]) e = q;
    blk2e[tid] = e;
  }
  if (tid < 8) {
    out_tail[1 + tid] = frac_sum[tid] / 4096.f;
    out_tail[9 + tid] = (float)counts[tid];
  }
}

// ---------------------------------------------------------------- assign rows
__global__ __launch_bounds__(256) void k_assign(const int* __restrict__ topi,
                                                const float* __restrict__ wslot,
                                                const int* __restrict__ offsets,
                                                int* __restrict__ cursor,
                                                int* __restrict__ row2tok, float* __restrict__ roww) {
  int g = blockIdx.x * 256 + threadIdx.x;
  if (g >= 8192) return;
  int t = g >> 1;
  int e = topi[g];
  int pos = atomicAdd(&cursor[e], 1);
  int r = offsets[e] + pos;
  row2tok[r] = t;
  roww[r] = wslot[g];
}

// ---------------------------------------------------------------- gather x rows -> bf16
__global__ __launch_bounds__(64) void k_gather(const float* __restrict__ x,
                                               const int* __restrict__ row2tok,
                                               ushort_t* __restrict__ xg) {
  int r = blockIdx.x;
  int t = row2tok[r];
  ushort4* dst = (ushort4*)(xg + (size_t)r * 1024);
  if (t < 0) {
    ushort4 z; z.x = z.y = z.z = z.w = 0;
    for (int i = threadIdx.x; i < 256; i += 64) dst[i] = z;
  } else {
    const floatx4* src = (const floatx4*)(x + (size_t)t * 1024);
    for (int i = threadIdx.x; i < 256; i += 64) {
      floatx4 v = src[i];
      ushort4 o; o.x = f2bf(v.x); o.y = f2bf(v.y); o.z = f2bf(v.z); o.w = f2bf(v.w);
      dst[i] = o;
    }
  }
}

// ---------------------------------------------------------------- out = (w0+w1) * x
__global__ __launch_bounds__(256) void k_init_out(const float* __restrict__ x,
                                                  const float* __restrict__ swsum,
                                                  float* __restrict__ out) {
  int g = blockIdx.x * 256 + threadIdx.x;
  float s = swsum[g >> 8];
  floatx4 v = ((const floatx4*)x)[g];
  ((floatx4*)out)[g] = v * s;
}

// ---------------------------------------------------------------- GEMM1: h = xg @ A_e^T + a_bias -> bf16
// m97-style: 128x128 tile, BK=64, 256 thr / 4 waves (2M x 2N), acc 4x4/wave,
// double-buffered LDS (4 x 16 KB = 64 KB -> 2 blocks/CU), gload_lds(16B),
// source-side XOR chunk swizzle (read uses same XOR; 0 conflicts measured).
// Simple 2-phase: stage(next) -> compute(cur) -> __syncthreads -> flip.
__global__ __launch_bounds__(256, 2) void k_gemm1(const ushort_t* __restrict__ Aop0,
                                                  const ushort_t* __restrict__ Wall,
                                                  const float* __restrict__ bias,
                                                  const int* __restrict__ blk2e,
                                                  ushort_t* __restrict__ hout) {
  const int K = 1024, N = 4096;
  int gx = gridDim.x;                      // 32
  int nwg = gx * gridDim.y;                // 2560
  int flat = blockIdx.y * gx + blockIdx.x;
  int qq = nwg >> 3, rr = nwg & 7;
  int xcd = flat & 7, idx = flat >> 3;
  int swz = (xcd < rr ? xcd * (qq + 1) : rr * (qq + 1) + (xcd - rr) * qq) + idx;
  int rb = swz / gx, nb = swz - rb * gx;
  int e = blk2e[rb >> 1];
  if (e < 0) return;
  const ushort_t* Aop = Aop0 + (size_t)rb * 128 * K;
  const ushort_t* Bop = Wall + (size_t)e * N * K + (size_t)nb * 128 * K;

  __shared__ ushort_t As[2][8192], Bs[2][8192];   // 16 KB each -> 64 KB total

  int tid = threadIdx.x, lane = tid & 63, wv = tid >> 6;
  int l15 = lane & 15, q = lane >> 4;
  int wm = (wv & 1) << 6, wn = (wv >> 1) << 6;
  floatx4 acc[4][4];
#pragma unroll
  for (int i = 0; i < 4; i++)
#pragma unroll
    for (int j = 0; j < 4; j++) acc[i][j] = (floatx4){0.f, 0.f, 0.f, 0.f};

  // staging: r=0..3: row = r*32 + (tid>>3), slot = tid&7
  //   global col-chunk pre-swizzled: slot ^ (row&7); LDS dest linear per wave.
  int srow = tid >> 3, schunk = tid & 7;

  auto stage = [&](int kt, int buf) {
#pragma unroll
    for (int r = 0; r < 4; ++r) {
      int row = (r << 5) + srow;
      size_t goff = (size_t)row * K + (size_t)(kt << 6) + (size_t)((schunk ^ (row & 7)) << 3);
      int loff = ((r << 8) + (wv << 6)) << 3;    // ushort index, wave-uniform base
      stage16(Aop + goff, &As[buf][loff]);
      stage16(Bop + goff, &Bs[buf][loff]);
    }
  };

  stage(0, 0);
  __syncthreads();
  int cur = 0;
  for (int kt = 0; kt < 16; ++kt) {
    if (kt + 1 < 16) stage(kt + 1, cur ^ 1);
    const ushort_t* Ab = As[cur];
    const ushort_t* Bb = Bs[cur];
#pragma unroll
    for (int kc = 0; kc < 2; ++kc) {
      int cw = (kc << 2) + q;
      shortx8 af[4], bfv[4];
#pragma unroll
      for (int i = 0; i < 4; ++i) {
        int row = wm + i * 16 + l15;
        af[i] = *(const shortx8*)(Ab + (row << 6) + ((cw ^ (row & 7)) << 3));
      }
#pragma unroll
      for (int j = 0; j < 4; ++j) {
        int row = wn + j * 16 + l15;
        bfv[j] = *(const shortx8*)(Bb + (row << 6) + ((cw ^ (row & 7)) << 3));
      }
#pragma unroll
      for (int i = 0; i < 4; ++i)
#pragma unroll
        for (int j = 0; j < 4; ++j)
          acc[i][j] = __builtin_amdgcn_mfma_f32_16x16x32_bf16(af[i], bfv[j], acc[i][j], 0, 0, 0);
    }
    __syncthreads();
    cur ^= 1;
  }

  const float* be = bias + (size_t)e * N + (size_t)nb * 128;
  ushort_t* hp = hout + (size_t)(rb * 128) * N + (size_t)nb * 128;
#pragma unroll
  for (int j = 0; j < 4; ++j) {
    int n = wn + j * 16 + l15;
    float bv = be[n];
#pragma unroll
    for (int i = 0; i < 4; ++i)
#pragma unroll
      for (int r = 0; r < 4; ++r) {
        int m = wm + i * 16 + (q << 2) + r;          // D row = quad*4 + reg
        hp[(size_t)m * N + n] = f2bf(acc[i][j][r] + bv);
      }
  }
}

// ---------------------------------------------------------------- GEMM2: f = h @ B_e^T (+bias iff z==0);
// atomicAdd(out[tok], roww*f). R4 structure: 256x256 tile, BK=64, 8 waves,
// dbuf 128 KB LDS, gload_lds(16B), 2-phase, split-K via gridDim.z.
__global__ __launch_bounds__(512, 2) void k_gemm2(const ushort_t* __restrict__ Aop0,
                                                  const ushort_t* __restrict__ Wall,
                                                  const float* __restrict__ bias,
                                                  const int* __restrict__ blk2e,
                                                  int K, int N,
                                                  float* __restrict__ outp,
                                                  const int* __restrict__ row2tok,
                                                  const float* __restrict__ roww) {
  int gx = gridDim.x;
  int nwg = gx * gridDim.y;
  int flat = blockIdx.y * gx + blockIdx.x;
  int qq = nwg >> 3, rr = nwg & 7;
  int xcd = flat & 7, idx = flat >> 3;
  int swz = (xcd < rr ? xcd * (qq + 1) : rr * (qq + 1) + (xcd - rr) * qq) + idx;
  int rb = swz / gx, nb = swz - rb * gx;

  int e = blk2e[rb];
  if (e < 0) return;
  int Kslice = K / gridDim.z;
  int kbase = blockIdx.z * Kslice;
  const ushort_t* Aop = Aop0 + (size_t)rb * 256 * K + kbase;
  const ushort_t* Bop = Wall + (size_t)e * N * K + (size_t)nb * 256 * K + kbase;

  __shared__ ushort_t As[2][16384], Bs[2][16384];   // 32 KB per buffer

  int tid = threadIdx.x, lane = tid & 63, wv = tid >> 6;
  int l15 = lane & 15, q = lane >> 4;
  int wm = (wv >> 2) << 7;   // 0 or 128
  int wn = (wv & 3) << 6;    // 0..192

  floatx4 acc[8][4];
#pragma unroll
  for (int i = 0; i < 8; i++)
#pragma unroll
    for (int j = 0; j < 4; j++) acc[i][j] = (floatx4){0.f, 0.f, 0.f, 0.f};

  int srow = tid >> 3;                     // 0..63
  int schunk = tid & 7;
  int ksteps = Kslice >> 6;
  int cur = 0;

  auto stage = [&](int kt, int buf) {
#pragma unroll
    for (int r = 0; r < 4; ++r) {
      int row = (r << 6) + srow;
      size_t goff = (size_t)row * K + (size_t)(kt << 6) + (size_t)((schunk ^ (row & 7)) << 3);
      int loff = ((r << 9) + (wv << 6)) << 3;    // ushort index, wave-uniform base
      stage16(Aop + goff, &As[buf][loff]);
      stage16(Bop + goff, &Bs[buf][loff]);
    }
  };

  stage(0, 0);
  __syncthreads();
  for (int ks = 0; ks < ksteps; ++ks) {
    if (ks + 1 < ksteps) stage(ks + 1, cur ^ 1);
    const ushort_t* Ab = As[cur];
    const ushort_t* Bb = Bs[cur];
#pragma unroll
    for (int kc = 0; kc < 2; ++kc) {
      int cw = (kc << 2) + q;
      shortx8 af[8], bfv[4];
#pragma unroll
      for (int i = 0; i < 8; ++i) {
        int row = wm + i * 16 + l15;
        af[i] = *(const shortx8*)(Ab + (row << 6) + ((cw ^ (row & 7)) << 3));
      }
#pragma unroll
      for (int j = 0; j < 4; ++j) {
        int row = wn + j * 16 + l15;
        bfv[j] = *(const shortx8*)(Bb + (row << 6) + ((cw ^ (row & 7)) << 3));
      }
#pragma unroll
      for (int i = 0; i < 8; ++i)
#pragma unroll
        for (int j = 0; j < 4; ++j)
          acc[i][j] = __builtin_amdgcn_mfma_f32_16x16x32_bf16(af[i], bfv[j], acc[i][j], 0, 0, 0);
    }
    __syncthreads();
    cur ^= 1;
  }

  const float* be = bias + (size_t)e * N + (size_t)nb * 256;
  bool addb = (blockIdx.z == 0);
  float bvv[4];
#pragma unroll
  for (int j = 0; j < 4; ++j) bvv[j] = addb ? be[wn + j * 16 + l15] : 0.f;
#pragma unroll
  for (int i = 0; i < 8; ++i)
#pragma unroll
    for (int r = 0; r < 4; ++r) {
      int m = wm + i * 16 + (q << 2) + r;
      int grow = rb * 256 + m;
      int tok = row2tok[grow];
      if (tok < 0) continue;
      float w = roww[grow];
      float* op = outp + (size_t)tok * 1024 + nb * 256;
#pragma unroll
      for (int j = 0; j < 4; ++j) {
        int n = wn + j * 16 + l15;
        atomicAdd(op + n, (acc[i][j][r] + bvv[j]) * w);
      }
    }
}

// ============================================================================
extern "C" void kernel_launch(void* const* d_in, const int* in_sizes, int n_in,
                              void* d_out, int out_size, void* d_ws, size_t ws_size,
                              hipStream_t stream) {
  (void)in_sizes; (void)n_in; (void)out_size; (void)ws_size;
  const float* x      = (const float*)d_in[0];
  const float* Wp     = (const float*)d_in[1];
  const float* bp     = (const float*)d_in[2];
  const float* sim    = (const float*)d_in[3];
  const float* temp   = (const float*)d_in[4];
  const float* A      = (const float*)d_in[5];
  const float* a_bias = (const float*)d_in[6];
  const float* Bw     = (const float*)d_in[7];
  const float* b_bias = (const float*)d_in[8];
  float* out = (float*)d_out;

  char* ws = (char*)d_ws;
  ushort_t* Abf    = (ushort_t*)(ws);                     //  67,108,864 B
  ushort_t* Bbf    = (ushort_t*)(ws + 67108864);          //  67,108,864 B
  ushort_t* xg     = (ushort_t*)(ws + 134217728);         //  20,971,520 B
  ushort_t* h      = (ushort_t*)(ws + 155189248);         //  83,886,080 B
  float*    proj   = (float*)   (ws + 239075328);         //   4,194,304 B
  int*      topi   = (int*)     (ws + 243269632);
  float*    wslot  = (float*)   (ws + 243302400);
  float*    swsum  = (float*)   (ws + 243335168);
  int*      row2tok= (int*)     (ws + 243351552);
  float*    roww   = (float*)   (ws + 243392512);
  int*      counts = (int*)     (ws + 243433472);
  int*      cursor = (int*)     (ws + 243433504);
  int*      offsets= (int*)     (ws + 243433536);
  int*      blk2e  = (int*)     (ws + 243433600);
  float*    fracs  = (float*)   (ws + 243433760);

  k_cvt<<<32768, 256, 0, stream>>>(A,  Abf, 8388608);
  k_cvt<<<32768, 256, 0, stream>>>(Bw, Bbf, 8388608);
  k_small_init<<<40, 256, 0, stream>>>(counts, cursor, fracs, row2tok);
  k_proj<<<256, 256, 0, stream>>>(x, Wp, bp, proj);
  k_gate<<<32, 128, 0, stream>>>(proj, sim, temp, topi, wslot, swsum, fracs, counts);
  k_scan<<<1, 128, 0, stream>>>(counts, fracs, offsets, blk2e, out + 4194304);
  k_assign<<<32, 256, 0, stream>>>(topi, wslot, offsets, cursor, row2tok, roww);
  k_gather<<<ROWS_PAD, 64, 0, stream>>>(x, row2tok, xg);
  k_init_out<<<4096, 256, 0, stream>>>(x, swsum, out);
  // GEMM1: h[r][j] = xg[r] . A_e[j] + a_bias  (K=1024, N=4096), 128^2 tiles, grid 32x80
  k_gemm1<<<dim3(32, MBLK1, 1), 256, 0, stream>>>(xg, Abf, a_bias, blk2e, h);
  // GEMM2: f = h . B_e^T + b_bias; out[tok] += roww * f  (K=4096, N=1024, 256^2, split-K x2)
  k_gemm2<<<dim3(4, MBLK, 2), 512, 0, stream>>>(h, Bbf, b_bias, blk2e, 4096, 1024,
                                                out, row2tok, roww);
}

// Round 4
// 736.460 us; speedup vs baseline: 1.1317x; 1.0508x over previous
//
#include <hip/hip_runtime.h>
#include <stdint.h>

// ============================================================================
// MoE adapter layer, sparse top-2 dispatch, bf16 MFMA expert GEMMs.
// R7: tail-kill + structural A/B in one run.
//  - R6 analysis: gemm2 (256^2, 1 blk/CU) = 370 TF raw = 660 TF balance-
//    corrected (= m248's ceiling for that structure). Bottleneck is the
//    half-empty second dispatch round, not the inner loop.
//  - k_gemm2 -> m97-exact: 128x128 tile, BK=64, SINGLE 32 KB LDS buffer,
//    stage -> barrier -> compute -> barrier, gload_lds(16B)+XOR swizzle,
//    4 blocks/CU (launch_bounds(256,4)). Grid (8,80,2)=1280 -> ~1.1 rounds.
//    Cross-block co-residency hides the per-tile vmcnt drain (m114).
//  - k_gemm1 unchanged from R6 (128^2 dbuf, 2 blk/CU) = in-run control.
//  - k_cvt x2 fused into one launch; k_gather re-blocked to 256 thr.
// Gating kept entirely fp32 (top-k decision boundaries are flip-sensitive).
// ============================================================================

typedef __attribute__((ext_vector_type(4))) float floatx4;
typedef __attribute__((ext_vector_type(8))) short shortx8;
typedef unsigned short ushort_t;

#define T_TOKENS 4096
#define D_DIM    1024
#define E_EXP    8
#define H_DIM    4096
#define P_DIM    256
#define ROWS_PAD 10240  // 8192 rows + per-expert 256-padding (max 10232)
#define MBLK     40     // ROWS_PAD / 256   (scan granularity)
#define MBLK1    80     // ROWS_PAD / 128   (gemm row-blocks)

__device__ __forceinline__ ushort_t f2bf(float f) {
  union { float f; unsigned int u; } c; c.f = f;
  unsigned int u = c.u;
  unsigned int r = u + 0x7FFFu + ((u >> 16) & 1u);  // RNE
  return (ushort_t)(r >> 16);
}

__device__ __forceinline__ void stage16(const ushort_t* g, ushort_t* l) {
  __builtin_amdgcn_global_load_lds((const __attribute__((address_space(1))) void*)g,
                                   (__attribute__((address_space(3))) void*)l, 16, 0, 0);
}

// ---------------------------------------------------------------- convert (both weight tensors, one launch)
__global__ __launch_bounds__(256) void k_cvt2(const float* __restrict__ srcA,
                                              const float* __restrict__ srcB,
                                              ushort_t* __restrict__ dstA,
                                              ushort_t* __restrict__ dstB) {
  int g = blockIdx.x * 256 + threadIdx.x;       // 0 .. 16777215
  const float* s; ushort_t* d; int i;
  if (g < 8388608) { s = srcA; d = dstA; i = g; }
  else             { s = srcB; d = dstB; i = g - 8388608; }
  floatx4 v = ((const floatx4*)s)[i];
  ushort4 o; o.x = f2bf(v.x); o.y = f2bf(v.y); o.z = f2bf(v.z); o.w = f2bf(v.w);
  ((ushort4*)d)[i] = o;
}

// ---------------------------------------------------------------- small init
__global__ __launch_bounds__(256) void k_small_init(int* counts, int* cursor,
                                                    float* frac_sum, int* row2tok) {
  int g = blockIdx.x * 256 + threadIdx.x;
  if (g < 8) { counts[g] = 0; cursor[g] = 0; frac_sum[g] = 0.f; }
  if (g < ROWS_PAD) row2tok[g] = -1;
}

// ---------------------------------------------------------------- proj = x @ Wp^T + bp   (fp32)
__global__ __launch_bounds__(256) void k_proj(const float* __restrict__ x,
                                              const float* __restrict__ Wp,
                                              const float* __restrict__ bp,
                                              float* __restrict__ proj) {
  __shared__ float Wc[256 * 36];
  __shared__ float Xc[16 * 36];
  int tid = threadIdx.x;
  int t0 = blockIdx.x * 16;
  int cg = tid & 31, tg = tid >> 5;
  floatx4 acc[2][8];
#pragma unroll
  for (int a = 0; a < 2; a++)
#pragma unroll
    for (int b = 0; b < 8; b++) acc[a][b] = (floatx4){0.f, 0.f, 0.f, 0.f};
  for (int kc = 0; kc < 32; ++kc) {
    int k0 = kc * 32;
    __syncthreads();
#pragma unroll
    for (int it = 0; it < 8; ++it) {
      int f = it * 256 + tid;
      int j = f >> 3, kk = (f & 7) << 2;
      floatx4 v = *(const floatx4*)(Wp + j * 1024 + k0 + kk);
      *(floatx4*)(Wc + j * 36 + kk) = v;
    }
    if (tid < 128) {
      int t = tid >> 3, kk = (tid & 7) << 2;
      floatx4 v = *(const floatx4*)(x + (size_t)(t0 + t) * 1024 + k0 + kk);
      *(floatx4*)(Xc + t * 36 + kk) = v;
    }
    __syncthreads();
#pragma unroll
    for (int k4 = 0; k4 < 8; ++k4) {
      floatx4 xv[2], wv[8];
#pragma unroll
      for (int tt = 0; tt < 2; tt++) xv[tt] = *(floatx4*)(Xc + (tg * 2 + tt) * 36 + k4 * 4);
#pragma unroll
      for (int jj = 0; jj < 8; jj++) wv[jj] = *(floatx4*)(Wc + (cg + jj * 32) * 36 + k4 * 4);
#pragma unroll
      for (int tt = 0; tt < 2; tt++)
#pragma unroll
        for (int jj = 0; jj < 8; jj++) acc[tt][jj] += xv[tt] * wv[jj];
    }
  }
#pragma unroll
  for (int tt = 0; tt < 2; tt++)
#pragma unroll
    for (int jj = 0; jj < 8; jj++) {
      floatx4 a = acc[tt][jj];
      float s = (a.x + a.y) + (a.z + a.w);
      int t = t0 + tg * 2 + tt, j = cg + jj * 32;
      proj[t * 256 + j] = s + bp[j];
    }
}

// ---------------------------------------------------------------- gate
__global__ __launch_bounds__(128) void k_gate(const float* __restrict__ proj,
                                              const float* __restrict__ sim,
                                              const float* __restrict__ temp,
                                              int* __restrict__ topi, float* __restrict__ wslot,
                                              float* __restrict__ swsum,
                                              float* __restrict__ frac_sum, int* __restrict__ counts) {
  __shared__ float simT[8][256];
  __shared__ float snorm[8];
  __shared__ float fracs[8];
  __shared__ int cnts[8];
  int tid = threadIdx.x;
  for (int i = tid; i < 2048; i += 128) { int p = i >> 3, e = i & 7; simT[e][p] = sim[i]; }
  if (tid < 8) { fracs[tid] = 0.f; cnts[tid] = 0; }
  __syncthreads();
  if (tid < 8) {
    float s = 0.f;
    for (int p = 0; p < 256; p++) { float v = simT[tid][p]; s += v * v; }
    snorm[tid] = fmaxf(sqrtf(s), 1e-12f);
  }
  __syncthreads();
  int t = blockIdx.x * 128 + tid;
  floatx4 n4 = (floatx4){0.f, 0.f, 0.f, 0.f};
  floatx4 d4[8];
#pragma unroll
  for (int e = 0; e < 8; e++) d4[e] = (floatx4){0.f, 0.f, 0.f, 0.f};
  const floatx4* pr = (const floatx4*)(proj + t * 256);
  for (int k4 = 0; k4 < 64; ++k4) {
    floatx4 p = pr[k4];
    n4 += p * p;
#pragma unroll
    for (int e = 0; e < 8; e++) d4[e] += p * *(const floatx4*)(&simT[e][k4 * 4]);
  }
  float nrm = fmaxf(sqrtf((n4.x + n4.y) + (n4.z + n4.w)), 1e-12f);
  float scale = expf(fminf(temp[0], 4.6051701859880914f));  // log(100)
  float pe[8];
  float mx = -1e30f;
#pragma unroll
  for (int e = 0; e < 8; e++) {
    float d = (d4[e].x + d4[e].y) + (d4[e].z + d4[e].w);
    pe[e] = d / (nrm * snorm[e]) * scale;
    mx = fmaxf(mx, pe[e]);
  }
  float sum = 0.f;
#pragma unroll
  for (int e = 0; e < 8; e++) { pe[e] = expf(pe[e] - mx); sum += pe[e]; }
#pragma unroll
  for (int e = 0; e < 8; e++) pe[e] /= sum;
  int i0 = 0;
#pragma unroll
  for (int e = 1; e < 8; e++) if (pe[e] > pe[i0]) i0 = e;
  int i1 = (i0 == 0) ? 1 : 0;
#pragma unroll
  for (int e = 0; e < 8; e++) if (e != i1 && e != i0 && pe[e] > pe[i1]) i1 = e;
  float v0 = pe[i0], v1 = pe[i1];
  float s2 = v0 + v1 + 1e-8f;
  float w0 = v0 / s2, w1 = v1 / s2;
  topi[t * 2] = i0; topi[t * 2 + 1] = i1;
  wslot[t * 2] = w0; wslot[t * 2 + 1] = w1;
  swsum[t] = w0 + w1;
#pragma unroll
  for (int e = 0; e < 8; e++) atomicAdd(&fracs[e], pe[e]);
  atomicAdd(&cnts[i0], 1); atomicAdd(&cnts[i1], 1);
  __syncthreads();
  if (tid < 8) { atomicAdd(&frac_sum[tid], fracs[tid]); atomicAdd(&counts[tid], cnts[tid]); }
}

// ---------------------------------------------------------------- scan (256-aligned expert segments)
__global__ void k_scan(const int* __restrict__ counts, const float* __restrict__ frac_sum,
                       int* __restrict__ offsets, int* __restrict__ blk2e,
                       float* __restrict__ out_tail) {
  __shared__ int offs[9];
  if (threadIdx.x == 0) {
    int off = 0;
    for (int e = 0; e < 8; e++) { offs[e] = off; off += ((counts[e] + 255) >> 8) << 8; }
    offs[8] = off;
    for (int e = 0; e < 9; e++) offsets[e] = offs[e];
    float aux = 0.f;
    for (int e = 0; e < 8; e++) { float fr = frac_sum[e] / 4096.f; aux += (fr - 0.125f) * (fr - 0.125f); }
    out_tail[0] = aux;
  }
  __syncthreads();
  int tid = threadIdx.x;
  if (tid < MBLK) {
    int r = tid * 256, e = -1;
    for (int q = 0; q < 8; q++) if (r >= offs[q] && r < offs[q + 1]) e = q;
    blk2e[tid] = e;
  }
  if (tid < 8) {
    out_tail[1 + tid] = frac_sum[tid] / 4096.f;
    out_tail[9 + tid] = (float)counts[tid];
  }
}

// ---------------------------------------------------------------- assign rows
__global__ __launch_bounds__(256) void k_assign(const int* __restrict__ topi,
                                                const float* __restrict__ wslot,
                                                const int* __restrict__ offsets,
                                                int* __restrict__ cursor,
                                                int* __restrict__ row2tok, float* __restrict__ roww) {
  int g = blockIdx.x * 256 + threadIdx.x;
  if (g >= 8192) return;
  int t = g >> 1;
  int e = topi[g];
  int pos = atomicAdd(&cursor[e], 1);
  int r = offsets[e] + pos;
  row2tok[r] = t;
  roww[r] = wslot[g];
}

// ---------------------------------------------------------------- gather x rows -> bf16 (4 rows / 256-thr block)
__global__ __launch_bounds__(256) void k_gather(const float* __restrict__ x,
                                                const int* __restrict__ row2tok,
                                                ushort_t* __restrict__ xg) {
  int r = blockIdx.x * 4 + (threadIdx.x >> 6);
  int l = threadIdx.x & 63;
  int t = row2tok[r];
  ushort4* dst = (ushort4*)(xg + (size_t)r * 1024);
  if (t < 0) {
    ushort4 z; z.x = z.y = z.z = z.w = 0;
    for (int i = l; i < 256; i += 64) dst[i] = z;
  } else {
    const floatx4* src = (const floatx4*)(x + (size_t)t * 1024);
    for (int i = l; i < 256; i += 64) {
      floatx4 v = src[i];
      ushort4 o; o.x = f2bf(v.x); o.y = f2bf(v.y); o.z = f2bf(v.z); o.w = f2bf(v.w);
      dst[i] = o;
    }
  }
}

// ---------------------------------------------------------------- out = (w0+w1) * x
__global__ __launch_bounds__(256) void k_init_out(const float* __restrict__ x,
                                                  const float* __restrict__ swsum,
                                                  float* __restrict__ out) {
  int g = blockIdx.x * 256 + threadIdx.x;
  float s = swsum[g >> 8];
  floatx4 v = ((const floatx4*)x)[g];
  ((floatx4*)out)[g] = v * s;
}

// ---------------------------------------------------------------- GEMM1: h = xg @ A_e^T + a_bias -> bf16
// R6 structure (control): 128x128 tile, BK=64, 4 waves, acc 4x4, dbuf 64 KB,
// gload_lds(16B) + source-XOR swizzle, 2-phase, 2 blocks/CU.
__global__ __launch_bounds__(256, 2) void k_gemm1(const ushort_t* __restrict__ Aop0,
                                                  const ushort_t* __restrict__ Wall,
                                                  const float* __restrict__ bias,
                                                  const int* __restrict__ blk2e,
                                                  ushort_t* __restrict__ hout) {
  const int K = 1024, N = 4096;
  int gx = gridDim.x;                      // 32
  int nwg = gx * gridDim.y;                // 2560
  int flat = blockIdx.y * gx + blockIdx.x;
  int qq = nwg >> 3, rr = nwg & 7;
  int xcd = flat & 7, idx = flat >> 3;
  int swz = (xcd < rr ? xcd * (qq + 1) : rr * (qq + 1) + (xcd - rr) * qq) + idx;
  int rb = swz / gx, nb = swz - rb * gx;
  int e = blk2e[rb >> 1];
  if (e < 0) return;
  const ushort_t* Aop = Aop0 + (size_t)rb * 128 * K;
  const ushort_t* Bop = Wall + (size_t)e * N * K + (size_t)nb * 128 * K;

  __shared__ ushort_t As[2][8192], Bs[2][8192];   // 16 KB each -> 64 KB total

  int tid = threadIdx.x, lane = tid & 63, wv = tid >> 6;
  int l15 = lane & 15, q = lane >> 4;
  int wm = (wv & 1) << 6, wn = (wv >> 1) << 6;
  floatx4 acc[4][4];
#pragma unroll
  for (int i = 0; i < 4; i++)
#pragma unroll
    for (int j = 0; j < 4; j++) acc[i][j] = (floatx4){0.f, 0.f, 0.f, 0.f};

  int srow = tid >> 3, schunk = tid & 7;

  auto stage = [&](int kt, int buf) {
#pragma unroll
    for (int r = 0; r < 4; ++r) {
      int row = (r << 5) + srow;
      size_t goff = (size_t)row * K + (size_t)(kt << 6) + (size_t)((schunk ^ (row & 7)) << 3);
      int loff = ((r << 8) + (wv << 6)) << 3;    // ushort index, wave-uniform base
      stage16(Aop + goff, &As[buf][loff]);
      stage16(Bop + goff, &Bs[buf][loff]);
    }
  };

  stage(0, 0);
  __syncthreads();
  int cur = 0;
  for (int kt = 0; kt < 16; ++kt) {
    if (kt + 1 < 16) stage(kt + 1, cur ^ 1);
    const ushort_t* Ab = As[cur];
    const ushort_t* Bb = Bs[cur];
#pragma unroll
    for (int kc = 0; kc < 2; ++kc) {
      int cw = (kc << 2) + q;
      shortx8 af[4], bfv[4];
#pragma unroll
      for (int i = 0; i < 4; ++i) {
        int row = wm + i * 16 + l15;
        af[i] = *(const shortx8*)(Ab + (row << 6) + ((cw ^ (row & 7)) << 3));
      }
#pragma unroll
      for (int j = 0; j < 4; ++j) {
        int row = wn + j * 16 + l15;
        bfv[j] = *(const shortx8*)(Bb + (row << 6) + ((cw ^ (row & 7)) << 3));
      }
#pragma unroll
      for (int i = 0; i < 4; ++i)
#pragma unroll
        for (int j = 0; j < 4; ++j)
          acc[i][j] = __builtin_amdgcn_mfma_f32_16x16x32_bf16(af[i], bfv[j], acc[i][j], 0, 0, 0);
    }
    __syncthreads();
    cur ^= 1;
  }

  const float* be = bias + (size_t)e * N + (size_t)nb * 128;
  ushort_t* hp = hout + (size_t)(rb * 128) * N + (size_t)nb * 128;
#pragma unroll
  for (int j = 0; j < 4; ++j) {
    int n = wn + j * 16 + l15;
    float bv = be[n];
#pragma unroll
    for (int i = 0; i < 4; ++i)
#pragma unroll
      for (int r = 0; r < 4; ++r) {
        int m = wm + i * 16 + (q << 2) + r;          // D row = quad*4 + reg
        hp[(size_t)m * N + n] = f2bf(acc[i][j][r] + bv);
      }
  }
}

// ---------------------------------------------------------------- GEMM2: f = h @ B_e^T (+bias iff z==0);
// atomicAdd(out[tok], roww*f). R7: m97-exact 128x128 tile, BK=64, SINGLE
// 32 KB LDS buffer (stage -> barrier -> compute -> barrier), 4 blocks/CU.
__global__ __launch_bounds__(256, 4) void k_gemm2(const ushort_t* __restrict__ Aop0,
                                                  const ushort_t* __restrict__ Wall,
                                                  const float* __restrict__ bias,
                                                  const int* __restrict__ blk2e,
                                                  int K, int N,
                                                  float* __restrict__ outp,
                                                  const int* __restrict__ row2tok,
                                                  const float* __restrict__ roww) {
  int gx = gridDim.x;                      // 8
  int nwg = gx * gridDim.y;                // 640
  int flat = blockIdx.y * gx + blockIdx.x;
  int qq = nwg >> 3, rr = nwg & 7;
  int xcd = flat & 7, idx = flat >> 3;
  int swz = (xcd < rr ? xcd * (qq + 1) : rr * (qq + 1) + (xcd - rr) * qq) + idx;
  int rb = swz / gx, nb = swz - rb * gx;   // rb 0..79 (128-row blocks), nb 0..7

  int e = blk2e[rb >> 1];
  if (e < 0) return;
  int Kslice = K / gridDim.z;
  int kbase = blockIdx.z * Kslice;
  const ushort_t* Aop = Aop0 + (size_t)rb * 128 * K + kbase;
  const ushort_t* Bop = Wall + (size_t)e * N * K + (size_t)nb * 128 * K + kbase;

  __shared__ ushort_t As[8192], Bs[8192];  // 16 KB each -> 32 KB total

  int tid = threadIdx.x, lane = tid & 63, wv = tid >> 6;
  int l15 = lane & 15, q = lane >> 4;
  int wm = (wv & 1) << 6, wn = (wv >> 1) << 6;
  floatx4 acc[4][4];
#pragma unroll
  for (int i = 0; i < 4; i++)
#pragma unroll
    for (int j = 0; j < 4; j++) acc[i][j] = (floatx4){0.f, 0.f, 0.f, 0.f};

  int srow = tid >> 3, schunk = tid & 7;
  int ksteps = Kslice >> 6;

  for (int kt = 0; kt < ksteps; ++kt) {
#pragma unroll
    for (int r = 0; r < 4; ++r) {
      int row = (r << 5) + srow;
      size_t goff = (size_t)row * K + (size_t)(kt << 6) + (size_t)((schunk ^ (row & 7)) << 3);
      int loff = ((r << 8) + (wv << 6)) << 3;
      stage16(Aop + goff, &As[loff]);
      stage16(Bop + goff, &Bs[loff]);
    }
    __syncthreads();   // vmcnt(0) drain: staged tile visible to all waves
#pragma unroll
    for (int kc = 0; kc < 2; ++kc) {
      int cw = (kc << 2) + q;
      shortx8 af[4], bfv[4];
#pragma unroll
      for (int i = 0; i < 4; ++i) {
        int row = wm + i * 16 + l15;
        af[i] = *(const shortx8*)(As + (row << 6) + ((cw ^ (row & 7)) << 3));
      }
#pragma unroll
      for (int j = 0; j < 4; ++j) {
        int row = wn + j * 16 + l15;
        bfv[j] = *(const shortx8*)(Bs + (row << 6) + ((cw ^ (row & 7)) << 3));
      }
#pragma unroll
      for (int i = 0; i < 4; ++i)
#pragma unroll
        for (int j = 0; j < 4; ++j)
          acc[i][j] = __builtin_amdgcn_mfma_f32_16x16x32_bf16(af[i], bfv[j], acc[i][j], 0, 0, 0);
    }
    __syncthreads();   // reads done before next stage overwrites
  }

  const float* be = bias + (size_t)e * N + (size_t)nb * 128;
  bool addb = (blockIdx.z == 0);
#pragma unroll
  for (int j = 0; j < 4; ++j) {
    int n = wn + j * 16 + l15;
    float bv = addb ? be[n] : 0.f;
#pragma unroll
    for (int i = 0; i < 4; ++i)
#pragma unroll
      for (int r = 0; r < 4; ++r) {
        int m = wm + i * 16 + (q << 2) + r;
        int grow = rb * 128 + m;
        int tok = row2tok[grow];
        if (tok < 0) continue;
        float w = roww[grow];
        atomicAdd(outp + (size_t)tok * 1024 + (size_t)nb * 128 + n, (acc[i][j][r] + bv) * w);
      }
  }
}

// ============================================================================
extern "C" void kernel_launch(void* const* d_in, const int* in_sizes, int n_in,
                              void* d_out, int out_size, void* d_ws, size_t ws_size,
                              hipStream_t stream) {
  (void)in_sizes; (void)n_in; (void)out_size; (void)ws_size;
  const float* x      = (const float*)d_in[0];
  const float* Wp     = (const float*)d_in[1];
  const float* bp     = (const float*)d_in[2];
  const float* sim    = (const float*)d_in[3];
  const float* temp   = (const float*)d_in[4];
  const float* A      = (const float*)d_in[5];
  const float* a_bias = (const float*)d_in[6];
  const float* Bw     = (const float*)d_in[7];
  const float* b_bias = (const float*)d_in[8];
  float* out = (float*)d_out;

  char* ws = (char*)d_ws;
  ushort_t* Abf    = (ushort_t*)(ws);                     //  67,108,864 B
  ushort_t* Bbf    = (ushort_t*)(ws + 67108864);          //  67,108,864 B
  ushort_t* xg     = (ushort_t*)(ws + 134217728);         //  20,971,520 B
  ushort_t* h      = (ushort_t*)(ws + 155189248);         //  83,886,080 B
  float*    proj   = (float*)   (ws + 239075328);         //   4,194,304 B
  int*      topi   = (int*)     (ws + 243269632);
  float*    wslot  = (float*)   (ws + 243302400);
  float*    swsum  = (float*)   (ws + 243335168);
  int*      row2tok= (int*)     (ws + 243351552);
  float*    roww   = (float*)   (ws + 243392512);
  int*      counts = (int*)     (ws + 243433472);
  int*      cursor = (int*)     (ws + 243433504);
  int*      offsets= (int*)     (ws + 243433536);
  int*      blk2e  = (int*)     (ws + 243433600);
  float*    fracs  = (float*)   (ws + 243433760);

  k_cvt2<<<65536, 256, 0, stream>>>(A, Bw, Abf, Bbf);
  k_small_init<<<40, 256, 0, stream>>>(counts, cursor, fracs, row2tok);
  k_proj<<<256, 256, 0, stream>>>(x, Wp, bp, proj);
  k_gate<<<32, 128, 0, stream>>>(proj, sim, temp, topi, wslot, swsum, fracs, counts);
  k_scan<<<1, 128, 0, stream>>>(counts, fracs, offsets, blk2e, out + 4194304);
  k_assign<<<32, 256, 0, stream>>>(topi, wslot, offsets, cursor, row2tok, roww);
  k_gather<<<ROWS_PAD / 4, 256, 0, stream>>>(x, row2tok, xg);
  k_init_out<<<4096, 256, 0, stream>>>(x, swsum, out);
  // GEMM1: h[r][j] = xg[r] . A_e[j] + a_bias  (K=1024, N=4096), 128^2 tiles, grid 32x80
  k_gemm1<<<dim3(32, MBLK1, 1), 256, 0, stream>>>(xg, Abf, a_bias, blk2e, h);
  // GEMM2: f = h . B_e^T + b_bias; out[tok] += roww * f  (K=4096, N=1024, 128^2, split-K x2)
  k_gemm2<<<dim3(8, MBLK1, 2), 256, 0, stream>>>(h, Bbf, b_bias, blk2e, 4096, 1024,
                                                 out, row2tok, roww);
}